// Round 23
// baseline (336.081 us; speedup 1.0000x reference)
//
#include <hip/hip_runtime.h>
#include <hip/hip_bf16.h>

// Problem constants
#define Sq 256
#define Hd 4096
#define NH 128
#define Pd 64
#define Gg 8
#define Nn 128
#define D_INNER 8192            // NH*P
#define D_STATE 1024            // G*N
#define CONV_DIM 10240          // D_INNER + 2*D_STATE
#define IN_OUT 18560            // D_INNER + CONV_DIM + NH
#define DT_COL0 18432           // D_INNER + CONV_DIM (start of dt columns)
#define EPSI 1e-6f

typedef _Float16 f16x8 __attribute__((ext_vector_type(8)));
typedef _Float16 f16x2 __attribute__((ext_vector_type(2)));
typedef float f32x4 __attribute__((ext_vector_type(4)));

__device__ inline ushort f2h(float f) {
  _Float16 h = (_Float16)f;
  return __builtin_bit_cast(ushort, h);
}
__device__ inline float h2f(ushort u) {
  return (float)__builtin_bit_cast(_Float16, u);
}
__device__ inline ushort f2h_lo(float f, ushort hi) {
  float hf = (float)__builtin_bit_cast(_Float16, hi);
  _Float16 l = (_Float16)(f - hf);
  return __builtin_bit_cast(ushort, l);
}
__device__ inline f16x2 pkrtz(float a, float b) {
  return __builtin_bit_cast(f16x2, __builtin_amdgcn_cvt_pkrtz(a, b));
}

// ---------------- RMSNorm (input) -> fp16 hi + lo ----------------
__global__ __launch_bounds__(256) void rmsnorm_k(const float* __restrict__ x,
                                                 const float* __restrict__ w,
                                                 ushort* __restrict__ h_hi,
                                                 ushort* __restrict__ h_lo) {
  int s = blockIdx.x, t = threadIdx.x;
  const float4* row = reinterpret_cast<const float4*>(x + (size_t)s * Hd);
  const float4* wv  = reinterpret_cast<const float4*>(w);
  float4 v[4];
  float ss = 0.f;
#pragma unroll
  for (int i = 0; i < 4; i++) {
    v[i] = row[t + i * 256];
    ss += v[i].x * v[i].x + v[i].y * v[i].y + v[i].z * v[i].z + v[i].w * v[i].w;
  }
#pragma unroll
  for (int off = 32; off > 0; off >>= 1) ss += __shfl_xor(ss, off);
  __shared__ float red[4];
  if ((t & 63) == 0) red[t >> 6] = ss;
  __syncthreads();
  ss = red[0] + red[1] + red[2] + red[3];
  float scale = rsqrtf(ss * (1.f / (float)Hd) + EPSI);
  ushort4* hh = reinterpret_cast<ushort4*>(h_hi + (size_t)s * Hd);
  ushort4* hl = reinterpret_cast<ushort4*>(h_lo + (size_t)s * Hd);
#pragma unroll
  for (int i = 0; i < 4; i++) {
    float4 wi = wv[t + i * 256];
    float f0 = v[i].x * scale * wi.x, f1 = v[i].y * scale * wi.y;
    float f2 = v[i].z * scale * wi.z, f3 = v[i].w * scale * wi.w;
    ushort4 oh, ol;
    oh.x = f2h(f0); ol.x = f2h_lo(f0, oh.x);
    oh.y = f2h(f1); ol.y = f2h_lo(f1, oh.y);
    oh.z = f2h(f2); ol.z = f2h_lo(f2, oh.z);
    oh.w = f2h(f3); ol.w = f2h_lo(f3, oh.w);
    hh[t + i * 256] = oh;
    hl[t + i * 256] = ol;
  }
}

// ========== 256x64-tile phase-split GEMM (T3+T4+T5), BK=64, 8 waves ==========
// r18/r20 structure (best measured): ph0 = issue all 6 next-tile loads ->
// vmcnt(6) -> barrier -> 8 af + 2 bf(n=0) reads -> lgkm -> 8 MFMA -> barrier;
// ph1 = WRITE_B -> 2 bf(n=1) reads -> lgkm -> 8 MFMA -> barrier.
// A: global_load_lds, source pre-swizzled granule^=(row&7) (128B rows).
// B: reg-staged f32 -> pkrtz -> swizzled ds_write (same involution).
// z==0 plane -> C0 (f32). z>0 -> Cp + (z-1)*Sq*ldc (fp16).
__global__ __launch_bounds__(512) void gemm_8p(const ushort* __restrict__ A,
                                               const float* __restrict__ B,
                                               float* __restrict__ C0,
                                               ushort* __restrict__ Cp,
                                               int ldc, int K, int kLen) {
  __shared__ __align__(16) ushort As[2][256 * 64];   // 32 KB each
  __shared__ __align__(16) ushort Bs[2][64 * 64];    // 8 KB each
  int t = threadIdx.x;
  int wave = t >> 6, lane = t & 63;
  int wr = wave >> 1, wc = wave & 1;
  int frow = lane & 15, gq = lane >> 4;
  int bcol = blockIdx.x * 64;
  int z = blockIdx.z;
  int kStart = z * kLen;

  // --- A DMA source: part p covers rows [p*64, +64). Lane l of wave w ->
  // row = p*64 + w*8 + (l>>3), phys granule l&7; logical = (l&7)^(row&7).
  int agl = (lane & 7) ^ (lane >> 3);
  const ushort* ApG = A + (size_t)(wave * 8 + (lane >> 3)) * K + kStart + agl * 8;

  // --- B stage: thread t -> row t>>3 (0..63), phys granule t&7; logical = phys^(row&7).
  int brow = t >> 3, bgp = t & 7;
  int bgl = bgp ^ (brow & 7);
  const float* BpG = B + (size_t)(bcol + brow) * K + kStart + bgl * 8;
  int bDst = brow * 128 + bgp * 16;

  f32x4 acc[4][2] = {};
  float4 rb[2];
  const int NT = kLen / 64;

#define SB() __builtin_amdgcn_sched_barrier(0)
#define ISSUE_RB(kk) { rb[0] = *(const float4*)(BpG + (kk)); \
                       rb[1] = *(const float4*)(BpG + (kk) + 4); }
#define DMA_A4(buf, kk) { _Pragma("unroll") for (int p = 0; p < 4; ++p) \
    __builtin_amdgcn_global_load_lds( \
        (const __attribute__((address_space(1))) void*)(ApG + (size_t)p * 64 * K + (kk)), \
        (__attribute__((address_space(3))) void*)((char*)&As[0][0] + (buf) * 32768 + p * 8192 + wave * 1024), \
        16, 0, 0); }
#define WRITE_RB(buf) { union { f16x2 h2[4]; uint4 q; } u; \
    u.h2[0] = pkrtz(rb[0].x, rb[0].y); u.h2[1] = pkrtz(rb[0].z, rb[0].w); \
    u.h2[2] = pkrtz(rb[1].x, rb[1].y); u.h2[3] = pkrtz(rb[1].z, rb[1].w); \
    *(uint4*)((char*)&Bs[0][0] + (buf) * 8192 + bDst) = u.q; }

  // Prologue: fully stage tile 0 into buffer 0 (one exposed drain).
  ISSUE_RB(0)
  DMA_A4(0, 0)
  WRITE_RB(0)
  __syncthreads();

  f16x8 af[4][2];
  for (int i = 0; i < NT; ++i) {
    int cur = i & 1, nxt = cur ^ 1;
    bool nx = (i + 1 < NT);
    // ================= phase 0 =================
    if (nx) { ISSUE_RB((i + 1) * 64) DMA_A4(nxt, (i + 1) * 64) }
    SB();
    if (nx) { asm volatile("s_waitcnt vmcnt(6)" ::: "memory"); }   // keep next-tile 6 in flight
    else    { asm volatile("s_waitcnt vmcnt(0)" ::: "memory"); }
    SB();
    __builtin_amdgcn_s_barrier();      // all waves: tile i fully in LDS
    SB();
    f16x8 bfp[2];
#pragma unroll
    for (int m = 0; m < 4; ++m)
#pragma unroll
      for (int kh = 0; kh < 2; ++kh) {
        int row = wr * 64 + m * 16 + frow;
        af[m][kh] = *(const f16x8*)((const char*)&As[0][0] + cur * 32768 + row * 128 +
                                    ((((kh << 2) | gq) ^ (row & 7)) << 4));
      }
    {
      int row = wc * 32 + frow;        // n = 0
#pragma unroll
      for (int kh = 0; kh < 2; ++kh)
        bfp[kh] = *(const f16x8*)((const char*)&Bs[0][0] + cur * 8192 + row * 128 +
                                  ((((kh << 2) | gq) ^ (row & 7)) << 4));
    }
    asm volatile("s_waitcnt lgkmcnt(0)" ::: "memory");
    SB();
    __builtin_amdgcn_s_setprio(1);
#pragma unroll
    for (int kh = 0; kh < 2; ++kh)
#pragma unroll
      for (int m = 0; m < 4; ++m)
        acc[m][0] = __builtin_amdgcn_mfma_f32_16x16x32_f16(af[m][kh], bfp[kh], acc[m][0], 0, 0, 0);
    __builtin_amdgcn_s_setprio(0);
    SB();
    __builtin_amdgcn_s_barrier();
    SB();
    // ================= phase 1 =================
    if (nx) WRITE_RB(nxt)              // auto-waits rb; DMAs stay in flight
    {
      int row = wc * 32 + 16 + frow;   // n = 1
#pragma unroll
      for (int kh = 0; kh < 2; ++kh)
        bfp[kh] = *(const f16x8*)((const char*)&Bs[0][0] + cur * 8192 + row * 128 +
                                  ((((kh << 2) | gq) ^ (row & 7)) << 4));
    }
    asm volatile("s_waitcnt lgkmcnt(0)" ::: "memory");
    SB();
    __builtin_amdgcn_s_setprio(1);
#pragma unroll
    for (int kh = 0; kh < 2; ++kh)
#pragma unroll
      for (int m = 0; m < 4; ++m)
        acc[m][1] = __builtin_amdgcn_mfma_f32_16x16x32_f16(af[m][kh], bfp[kh], acc[m][1], 0, 0, 0);
    __builtin_amdgcn_s_setprio(0);
    SB();
    __builtin_amdgcn_s_barrier();
    SB();
  }
#undef SB
#undef ISSUE_RB
#undef DMA_A4
#undef WRITE_RB

  // Epilogue: C/D layout col=lane&15, row=(lane>>4)*4+r
  if (z == 0) {
#pragma unroll
    for (int m = 0; m < 4; ++m) {
      int row0 = wr * 64 + m * 16 + (lane >> 4) * 4;
#pragma unroll
      for (int n = 0; n < 2; ++n) {
        int col = bcol + wc * 32 + n * 16 + frow;
#pragma unroll
        for (int r = 0; r < 4; ++r)
          C0[(size_t)(row0 + r) * ldc + col] = acc[m][n][r];
      }
    }
  } else {
    ushort* Cz = Cp + (size_t)(z - 1) * Sq * ldc;
#pragma unroll
    for (int m = 0; m < 4; ++m) {
      int row0 = wr * 64 + m * 16 + (lane >> 4) * 4;
#pragma unroll
      for (int n = 0; n < 2; ++n) {
        int col = bcol + wc * 32 + n * 16 + frow;
#pragma unroll
        for (int r = 0; r < 4; ++r)
          Cz[(size_t)(row0 + r) * ldc + col] = f2h(acc[m][n][r]);
      }
    }
  }
}

// ---------------- reg-staged MFMA GEMM (dt-fixup, compensated fp16) ----
template<int BN, bool SPLIT>
__global__ __launch_bounds__(256) void gemm_mfma(const ushort* __restrict__ A_hi,
                                                 const ushort* __restrict__ A_lo,
                                                 const float* __restrict__ B,
                                                 float* __restrict__ C,
                                                 int ldc, int K, int kLen,
                                                 int bcol0, int M) {
  constexpr int BK = 64;
  constexpr int LDA = 72;
  constexpr int N_REP = BN / 32;
  constexpr int BQN = (BN == 128) ? 8 : 4;
  __shared__ __align__(16) ushort As[64 * LDA];
  __shared__ __align__(16) ushort Bs[BN * LDA];
  __shared__ __align__(16) ushort AsL[SPLIT ? 64 * LDA : 1];
  __shared__ __align__(16) ushort BsL[SPLIT ? BN * LDA : 1];

  int t = threadIdx.x;
  int wave = t >> 6, lane = t & 63;
  int wr = wave >> 1, wc = wave & 1;
  int frow = lane & 15, fk = (lane >> 4) * 8;
  int rowBase = blockIdx.x * 64;
  int bcol = bcol0 + blockIdx.y * BN;
  int ccol = blockIdx.y * BN;
  int kStart = blockIdx.z * kLen;
  C += (size_t)blockIdx.z * M * ldc;

  int arow = t >> 2, ak = (t & 3) * 16;
  const ushort* Ap  = A_hi + (size_t)(rowBase + arow) * K + ak;
  const ushort* ApL = SPLIT ? (A_lo + (size_t)(rowBase + arow) * K + ak) : nullptr;

  int brow, bq;
  if constexpr (BN == 128) { brow = t >> 1; bq = (t & 1) * 32; }
  else                     { brow = t >> 2; bq = (t & 3) * 16; }
  const float* Bp = B + (size_t)(bcol + brow) * K + bq;

  f32x4 acc[2][N_REP] = {};
  uint4 aPre[2], aPreL[2];
  float4 bPre[BQN];

  auto loadK = [&](int kk) {
    aPre[0] = *reinterpret_cast<const uint4*>(Ap + kk);
    aPre[1] = *reinterpret_cast<const uint4*>(Ap + kk + 8);
    if constexpr (SPLIT) {
      aPreL[0] = *reinterpret_cast<const uint4*>(ApL + kk);
      aPreL[1] = *reinterpret_cast<const uint4*>(ApL + kk + 8);
    }
#pragma unroll
    for (int j = 0; j < BQN; ++j)
      bPre[j] = *reinterpret_cast<const float4*>(Bp + kk + j * 4);
  };

  loadK(kStart);
  for (int ki = 0; ki < kLen; ki += BK) {
    __syncthreads();
    *reinterpret_cast<uint4*>(&As[arow * LDA + ak])     = aPre[0];
    *reinterpret_cast<uint4*>(&As[arow * LDA + ak + 8]) = aPre[1];
    if constexpr (SPLIT) {
      *reinterpret_cast<uint4*>(&AsL[arow * LDA + ak])     = aPreL[0];
      *reinterpret_cast<uint4*>(&AsL[arow * LDA + ak + 8]) = aPreL[1];
    }
    {
      ushort hb[BQN * 4];
      ushort lb[SPLIT ? BQN * 4 : 1];
      const float* bf = reinterpret_cast<const float*>(bPre);
#pragma unroll
      for (int j = 0; j < BQN * 4; ++j) {
        hb[j] = f2h(bf[j]);
        if constexpr (SPLIT) lb[j] = f2h_lo(bf[j], hb[j]);
      }
#pragma unroll
      for (int j = 0; j < BQN / 2; ++j)
        *reinterpret_cast<uint4*>(&Bs[brow * LDA + bq + j * 8]) =
            reinterpret_cast<const uint4*>(hb)[j];
      if constexpr (SPLIT) {
#pragma unroll
        for (int j = 0; j < BQN / 2; ++j)
          *reinterpret_cast<uint4*>(&BsL[brow * LDA + bq + j * 8]) =
              reinterpret_cast<const uint4*>(lb)[j];
      }
    }
    __syncthreads();
    if (ki + BK < kLen) loadK(kStart + ki + BK);
    f16x8 af[2][2], bfv[N_REP][2];
    f16x8 afL[SPLIT ? 2 : 1][2], bfL[SPLIT ? N_REP : 1][2];
#pragma unroll
    for (int m = 0; m < 2; ++m)
#pragma unroll
      for (int kh = 0; kh < 2; ++kh) {
        af[m][kh] = *reinterpret_cast<const f16x8*>(
            &As[(wr * 32 + m * 16 + frow) * LDA + kh * 32 + fk]);
        if constexpr (SPLIT)
          afL[m][kh] = *reinterpret_cast<const f16x8*>(
              &AsL[(wr * 32 + m * 16 + frow) * LDA + kh * 32 + fk]);
      }
#pragma unroll
    for (int n = 0; n < N_REP; ++n)
#pragma unroll
      for (int kh = 0; kh < 2; ++kh) {
        bfv[n][kh] = *reinterpret_cast<const f16x8*>(
            &Bs[(wc * (BN / 2) + n * 16 + frow) * LDA + kh * 32 + fk]);
        if constexpr (SPLIT)
          bfL[n][kh] = *reinterpret_cast<const f16x8*>(
              &BsL[(wc * (BN / 2) + n * 16 + frow) * LDA + kh * 32 + fk]);
      }
#pragma unroll
    for (int kh = 0; kh < 2; ++kh)
#pragma unroll
      for (int m = 0; m < 2; ++m)
#pragma unroll
        for (int n = 0; n < N_REP; ++n) {
          acc[m][n] = __builtin_amdgcn_mfma_f32_16x16x32_f16(af[m][kh], bfv[n][kh], acc[m][n], 0, 0, 0);
          if constexpr (SPLIT) {
            acc[m][n] = __builtin_amdgcn_mfma_f32_16x16x32_f16(af[m][kh], bfL[n][kh], acc[m][n], 0, 0, 0);
            acc[m][n] = __builtin_amdgcn_mfma_f32_16x16x32_f16(afL[m][kh], bfv[n][kh], acc[m][n], 0, 0, 0);
          }
        }
  }

#pragma unroll
  for (int m = 0; m < 2; ++m) {
    int row0 = rowBase + wr * 32 + m * 16 + (lane >> 4) * 4;
#pragma unroll
    for (int n = 0; n < N_REP; ++n) {
      int col = ccol + wc * (BN / 2) + n * 16 + frow;
#pragma unroll
      for (int r = 0; r < 4; ++r)
        C[(size_t)(row0 + r) * ldc + col] = acc[m][n][r];
    }
  }
}

// ---------------- reduce in_proj: proj(f32 plane0) += 1 fp16 plane ----------
__global__ __launch_bounds__(256) void reduce_in_k(float* __restrict__ proj,
                                                   const ushort* __restrict__ pp) {
  int i = blockIdx.x * 256 + threadIdx.x;   // float4 group index
  float4 o = reinterpret_cast<const float4*>(proj)[i];
  ushort4 hv = reinterpret_cast<const ushort4*>(pp)[i];
  o.x += h2f(hv.x); o.y += h2f(hv.y); o.z += h2f(hv.z); o.w += h2f(hv.w);
  reinterpret_cast<float4*>(proj)[i] = o;
}

// ---------------- Conv (K=4) + SiLU, with fused conv_state_out ----------------
__global__ __launch_bounds__(256) void conv_silu_k(const float* __restrict__ proj,
                                                   const float* __restrict__ cstate,
                                                   const float* __restrict__ cw,
                                                   const float* __restrict__ cb,
                                                   float* __restrict__ y,
                                                   float* __restrict__ out1) {
  int s = blockIdx.y;
  if (s == Sq) {   // fused conv_state_out
    int c = blockIdx.x * 256 + threadIdx.x;
#pragma unroll
    for (int tt = 0; tt < 3; ++tt)
      out1[c * 3 + tt] = proj[(size_t)(Sq - 3 + tt) * IN_OUT + D_INNER + c];
    return;
  }
  int c = blockIdx.x * 256 + threadIdx.x;  // 0..10239
  float acc = cb[c];
  float4 w4 = *reinterpret_cast<const float4*>(cw + c * 4);
  float wj[4] = {w4.x, w4.y, w4.z, w4.w};
#pragma unroll
  for (int j = 0; j < 4; j++) {
    int si = s + j - 3;
    float v = (si < 0) ? cstate[c * 3 + (si + 3)]
                       : proj[(size_t)si * IN_OUT + D_INNER + c];
    acc += wj[j] * v;
  }
  float sig = 1.f / (1.f + expf(-acc));
  y[(size_t)s * CONV_DIM + c] = acc * sig;
}

// ---------------- SSM scan: 4 blocks/head, float4 LDS reads, fused dt ---------
#define CS 16
__global__ __launch_bounds__(256) void ssm_scan_k(const float* __restrict__ y_conv,
                                                  const float* __restrict__ dtfix,
                                                  const float* __restrict__ dt_bias,
                                                  const float* __restrict__ sstate_in,
                                                  const float* __restrict__ A_log,
                                                  const float* __restrict__ D_param,
                                                  float* __restrict__ ys_out,
                                                  float* __restrict__ sstate_out) {
  int h = blockIdx.x >> 2;
  int pb = (blockIdx.x & 3) * 16;
  int t = threadIdx.x;
  int ng = t & 15, pl = t >> 4;
  int g = h >> 4;  // rep = NH/G = 16
  float A = -expf(A_log[h]);
  float Dp = D_param[h];
  float bias = dt_bias[h];

  float st[8];
  {
    const float* sp = sstate_in + ((size_t)h * Pd + pb + pl) * Nn + ng * 8;
    float4 v = *reinterpret_cast<const float4*>(sp);
    float4 w = *reinterpret_cast<const float4*>(sp + 4);
    st[0] = v.x; st[1] = v.y; st[2] = v.z; st[3] = v.w;
    st[4] = w.x; st[5] = w.y; st[6] = w.z; st[7] = w.w;
  }

  __shared__ __align__(16) float ybuf[CS][272];  // [0..15]=x, [16..143]=B, [144..271]=C
  __shared__ float dts[CS];
  int lr = t >> 4;
  int lc = t & 15;

  for (int ch = 0; ch < Sq / CS; ++ch) {
    int s0 = ch * CS;
    __syncthreads();
    const float* rowp = y_conv + (size_t)(s0 + lr) * CONV_DIM;
#pragma unroll
    for (int j = 0; j < 5; ++j) {
      int c = lc + 16 * j;  // f4 slot 0..79; 68 used
      if (c < 68) {
        const float* src;
        int off;
        if (c < 4)       { src = rowp + h * 64 + pb;                      off = c * 4; }
        else if (c < 36) { src = rowp + D_INNER + g * 128;                off = (c - 4) * 4; }
        else             { src = rowp + D_INNER + D_STATE + g * 128;      off = (c - 36) * 4; }
        int dst = (c < 4) ? c * 4 : (c < 36 ? 16 + (c - 4) * 4 : 144 + (c - 36) * 4);
        *reinterpret_cast<float4*>(&ybuf[lr][dst]) = *reinterpret_cast<const float4*>(src + off);
      }
    }
    if (t < CS) {   // fused dt: sum 32 split-K planes + bias -> softplus
      float v = bias;
      int idx = (s0 + t) * NH + h;
#pragma unroll
      for (int zz = 0; zz < 32; ++zz) v += dtfix[zz * (Sq * NH) + idx];
      dts[t] = (v > 20.f) ? v : log1pf(expf(v));
    }
    __syncthreads();

#pragma unroll 4
    for (int stp = 0; stp < CS; ++stp) {
      float dt = dts[stp];
      float dA = expf(dt * A);
      float x0 = ybuf[stp][pl];
      float dtx = dt * x0;
      float4 b0 = *reinterpret_cast<const float4*>(&ybuf[stp][16 + ng * 8]);
      float4 b1 = *reinterpret_cast<const float4*>(&ybuf[stp][16 + ng * 8 + 4]);
      float4 c0 = *reinterpret_cast<const float4*>(&ybuf[stp][144 + ng * 8]);
      float4 c1 = *reinterpret_cast<const float4*>(&ybuf[stp][144 + ng * 8 + 4]);
      float y0;
      st[0] = st[0] * dA + dtx * b0.x;  y0  = st[0] * c0.x;
      st[1] = st[1] * dA + dtx * b0.y;  y0 += st[1] * c0.y;
      st[2] = st[2] * dA + dtx * b0.z;  y0 += st[2] * c0.z;
      st[3] = st[3] * dA + dtx * b0.w;  y0 += st[3] * c0.w;
      st[4] = st[4] * dA + dtx * b1.x;  y0 += st[4] * c1.x;
      st[5] = st[5] * dA + dtx * b1.y;  y0 += st[5] * c1.y;
      st[6] = st[6] * dA + dtx * b1.z;  y0 += st[6] * c1.z;
      st[7] = st[7] * dA + dtx * b1.w;  y0 += st[7] * c1.w;
      y0 += __shfl_xor(y0, 1); y0 += __shfl_xor(y0, 2);
      y0 += __shfl_xor(y0, 4); y0 += __shfl_xor(y0, 8);
      if (ng == 0)
        ys_out[(size_t)(s0 + stp) * D_INNER + h * 64 + pb + pl] = y0 + Dp * x0;
    }
  }

  float* so = sstate_out + ((size_t)h * Pd + pb + pl) * Nn + ng * 8;
  *reinterpret_cast<float4*>(so)     = make_float4(st[0], st[1], st[2], st[3]);
  *reinterpret_cast<float4*>(so + 4) = make_float4(st[4], st[5], st[6], st[7]);
}

// ---------------- gate*silu + grouped RMSNorm -> fp16 ----------------
__global__ __launch_bounds__(256) void gated_norm_k(const float* __restrict__ ys,
                                                    const float* __restrict__ proj,
                                                    const float* __restrict__ w,
                                                    ushort* __restrict__ out_h) {
  int s = blockIdx.x, g = blockIdx.y, t = threadIdx.x;
  float vals[4];
  float ss = 0.f;
#pragma unroll
  for (int i = 0; i < 4; i++) {
    int d = g * 1024 + i * 256 + t;
    float gate = proj[(size_t)s * IN_OUT + d];
    float v = ys[(size_t)s * D_INNER + d] * (gate / (1.f + expf(-gate)));
    vals[i] = v;
    ss += v * v;
  }
#pragma unroll
  for (int off = 32; off > 0; off >>= 1) ss += __shfl_xor(ss, off);
  __shared__ float red[4];
  if ((t & 63) == 0) red[t >> 6] = ss;
  __syncthreads();
  ss = red[0] + red[1] + red[2] + red[3];
  float scale = rsqrtf(ss * (1.f / 1024.f) + EPSI);
#pragma unroll
  for (int i = 0; i < 4; i++) {
    int d = g * 1024 + i * 256 + t;
    out_h[(size_t)s * D_INNER + d] = f2h(vals[i] * scale * w[d]);
  }
}

// ---------------- out reduce: out0 = f32 plane0 + 7 fp16 planes + hidden ----
__global__ __launch_bounds__(256) void reduce_out_k(const float* __restrict__ p0,
                                                    const ushort* __restrict__ pph,
                                                    const float* __restrict__ hidden,
                                                    float* __restrict__ out0) {
  int i = blockIdx.x * 256 + threadIdx.x;
  const size_t PL = (size_t)Sq * Hd;
  float4 o = reinterpret_cast<const float4*>(hidden)[i];
  float4 a = reinterpret_cast<const float4*>(p0)[i];
  o.x += a.x; o.y += a.y; o.z += a.z; o.w += a.w;
#pragma unroll
  for (int zz = 0; zz < 7; ++zz) {
    ushort4 hv = reinterpret_cast<const ushort4*>(pph + zz * PL)[i];
    o.x += h2f(hv.x); o.y += h2f(hv.y); o.z += h2f(hv.z); o.w += h2f(hv.w);
  }
  reinterpret_cast<float4*>(out0)[i] = o;
}

extern "C" void kernel_launch(void* const* d_in, const int* in_sizes, int n_in,
                              void* d_out, int out_size, void* d_ws, size_t ws_size,
                              hipStream_t stream) {
  const float* hidden    = (const float*)d_in[0];
  const float* cstate_in = (const float*)d_in[1];
  const float* sstate_in = (const float*)d_in[2];
  const float* norm_w    = (const float*)d_in[3];
  const float* w_in      = (const float*)d_in[4];
  const float* conv_w    = (const float*)d_in[5];
  const float* conv_b    = (const float*)d_in[6];
  const float* A_log     = (const float*)d_in[7];
  const float* D_param   = (const float*)d_in[8];
  const float* dt_bias   = (const float*)d_in[9];
  const float* ssm_nw    = (const float*)d_in[10];
  const float* w_out     = (const float*)d_in[11];

  float* out0 = (float*)d_out;                    // [256,4096]
  float* out1 = out0 + (size_t)Sq * Hd;           // [10240,3]
  float* out2 = out1 + (size_t)CONV_DIM * 3;      // [128,64,128]

  ushort* h_hi  = (ushort*)d_ws;
  ushort* h_lo  = h_hi + (size_t)Sq * Hd;
  float*  proj  = (float*)(h_lo + (size_t)Sq * Hd);
  ushort* pp_in = (ushort*)(proj + (size_t)Sq * IN_OUT);      // 1 fp16 plane
  float*  y_conv = (float*)pp_in;                             // aliases pp_in post-reduce
  float*  dtp   = y_conv + (size_t)Sq * CONV_DIM;             // (hole)
  float*  ys    = dtp + (size_t)Sq * NH;
  ushort* ys_h  = (ushort*)(ys + (size_t)Sq * D_INNER);
  float*  dtfix = (float*)(ys_h + (size_t)Sq * D_INNER);      // 32 planes x 128KB = 4MB
  float*  op0    = (float*)d_ws;                              // out plane0 f32 (4MB)
  ushort* pp_out = (ushort*)(op0 + (size_t)Sq * Hd);          // 7 fp16 planes (14MB)

  // 1. RMSNorm -> fp16 hi/lo
  rmsnorm_k<<<Sq, 256, 0, stream>>>(hidden, norm_w, h_hi, h_lo);
  // 2. in_proj: phase-split 256x64 tiles, split-K x2. 580 blocks x 512 thr.
  gemm_8p<<<dim3(IN_OUT / 64, 1, 2), 512, 0, stream>>>(
      h_hi, w_in, proj, pp_in, IN_OUT, Hd, Hd / 2);
  // 2r. reduce split-K plane into proj
  reduce_in_k<<<(Sq * IN_OUT / 4) / 256, 256, 0, stream>>>(proj, pp_in);
  // 2b. dt columns, compensated fp16 (~f32), split-K x32 -> 256 blocks
  gemm_mfma<64, true><<<dim3(4, 2, 32), 256, 0, stream>>>(
      h_hi, h_lo, w_in, dtfix, NH, Hd, Hd / 32, DT_COL0, Sq);
  // 3. conv + silu (+fused conv_state_out on y==Sq row)
  conv_silu_k<<<dim3(CONV_DIM / 256, Sq + 1), 256, 0, stream>>>(
      proj, cstate_in, conv_w, conv_b, y_conv, out1);
  // 4. SSM scan (4 blocks/head, fused dt softplus)
  ssm_scan_k<<<NH * 4, 256, 0, stream>>>(y_conv, dtfix, dt_bias, sstate_in,
                                         A_log, D_param, ys, out2);
  // 5. gated + grouped RMSNorm -> fp16 A for out_proj
  gated_norm_k<<<dim3(Sq, Gg), 256, 0, stream>>>(ys, proj, ssm_nw, ys_h);
  // 6. out_proj: phase-split 256x64 tiles, split-K x8. 512 blocks (1 residency round).
  gemm_8p<<<dim3(Hd / 64, 1, 8), 512, 0, stream>>>(
      ys_h, w_out, op0, pp_out, Hd, D_INNER, D_INNER / 8);
  // 7. reduce 8 partials + residual
  reduce_out_k<<<(Sq * Hd / 4) / 256, 256, 0, stream>>>(op0, pp_out, hidden, out0);
}

// Round 24
// 318.075 us; speedup vs baseline: 1.0566x; 1.0566x over previous
//
#include <hip/hip_runtime.h>
#include <hip/hip_bf16.h>

// Problem constants
#define Sq 256
#define Hd 4096
#define NH 128
#define Pd 64
#define Gg 8
#define Nn 128
#define D_INNER 8192            // NH*P
#define D_STATE 1024            // G*N
#define CONV_DIM 10240          // D_INNER + 2*D_STATE
#define IN_OUT 18560            // D_INNER + CONV_DIM + NH
#define DT_COL0 18432           // D_INNER + CONV_DIM (start of dt columns)
#define EPSI 1e-6f

typedef _Float16 f16x8 __attribute__((ext_vector_type(8)));
typedef _Float16 f16x2 __attribute__((ext_vector_type(2)));
typedef float f32x4 __attribute__((ext_vector_type(4)));

__device__ inline ushort f2h(float f) {
  _Float16 h = (_Float16)f;
  return __builtin_bit_cast(ushort, h);
}
__device__ inline float h2f(ushort u) {
  return (float)__builtin_bit_cast(_Float16, u);
}
__device__ inline ushort f2h_lo(float f, ushort hi) {
  float hf = (float)__builtin_bit_cast(_Float16, hi);
  _Float16 l = (_Float16)(f - hf);
  return __builtin_bit_cast(ushort, l);
}
__device__ inline f16x2 pkrtz(float a, float b) {
  return __builtin_bit_cast(f16x2, __builtin_amdgcn_cvt_pkrtz(a, b));
}

// ---------------- RMSNorm (input) -> fp16 hi + lo ----------------
__global__ __launch_bounds__(256) void rmsnorm_k(const float* __restrict__ x,
                                                 const float* __restrict__ w,
                                                 ushort* __restrict__ h_hi,
                                                 ushort* __restrict__ h_lo) {
  int s = blockIdx.x, t = threadIdx.x;
  const float4* row = reinterpret_cast<const float4*>(x + (size_t)s * Hd);
  const float4* wv  = reinterpret_cast<const float4*>(w);
  float4 v[4];
  float ss = 0.f;
#pragma unroll
  for (int i = 0; i < 4; i++) {
    v[i] = row[t + i * 256];
    ss += v[i].x * v[i].x + v[i].y * v[i].y + v[i].z * v[i].z + v[i].w * v[i].w;
  }
#pragma unroll
  for (int off = 32; off > 0; off >>= 1) ss += __shfl_xor(ss, off);
  __shared__ float red[4];
  if ((t & 63) == 0) red[t >> 6] = ss;
  __syncthreads();
  ss = red[0] + red[1] + red[2] + red[3];
  float scale = rsqrtf(ss * (1.f / (float)Hd) + EPSI);
  ushort4* hh = reinterpret_cast<ushort4*>(h_hi + (size_t)s * Hd);
  ushort4* hl = reinterpret_cast<ushort4*>(h_lo + (size_t)s * Hd);
#pragma unroll
  for (int i = 0; i < 4; i++) {
    float4 wi = wv[t + i * 256];
    float f0 = v[i].x * scale * wi.x, f1 = v[i].y * scale * wi.y;
    float f2 = v[i].z * scale * wi.z, f3 = v[i].w * scale * wi.w;
    ushort4 oh, ol;
    oh.x = f2h(f0); ol.x = f2h_lo(f0, oh.x);
    oh.y = f2h(f1); ol.y = f2h_lo(f1, oh.y);
    oh.z = f2h(f2); ol.z = f2h_lo(f2, oh.z);
    oh.w = f2h(f3); ol.w = f2h_lo(f3, oh.w);
    hh[t + i * 256] = oh;
    hl[t + i * 256] = ol;
  }
}

// ========== 256x64-tile phase-split GEMM (T3+T4+T5), BK=64, 8 waves ==========
// r18/r20 structure (best measured): ph0 = issue all 6 next-tile loads ->
// vmcnt(6) -> barrier -> 8 af + 2 bf(n=0) reads -> lgkm -> 8 MFMA -> barrier;
// ph1 = WRITE_B -> 2 bf(n=1) reads -> lgkm -> 8 MFMA -> barrier.
// A: global_load_lds, source pre-swizzled granule^=(row&7) (128B rows).
// B: reg-staged f32 -> pkrtz -> swizzled ds_write (same involution).
// z==0 plane -> C0 (f32). z>0 -> Cp + (z-1)*Sq*ldc (fp16).
__global__ __launch_bounds__(512) void gemm_8p(const ushort* __restrict__ A,
                                               const float* __restrict__ B,
                                               float* __restrict__ C0,
                                               ushort* __restrict__ Cp,
                                               int ldc, int K, int kLen) {
  __shared__ __align__(16) ushort As[2][256 * 64];   // 32 KB each
  __shared__ __align__(16) ushort Bs[2][64 * 64];    // 8 KB each
  int t = threadIdx.x;
  int wave = t >> 6, lane = t & 63;
  int wr = wave >> 1, wc = wave & 1;
  int frow = lane & 15, gq = lane >> 4;
  int bcol = blockIdx.x * 64;
  int z = blockIdx.z;
  int kStart = z * kLen;

  // --- A DMA source: part p covers rows [p*64, +64). Lane l of wave w ->
  // row = p*64 + w*8 + (l>>3), phys granule l&7; logical = (l&7)^(row&7).
  int agl = (lane & 7) ^ (lane >> 3);
  const ushort* ApG = A + (size_t)(wave * 8 + (lane >> 3)) * K + kStart + agl * 8;

  // --- B stage: thread t -> row t>>3 (0..63), phys granule t&7; logical = phys^(row&7).
  int brow = t >> 3, bgp = t & 7;
  int bgl = bgp ^ (brow & 7);
  const float* BpG = B + (size_t)(bcol + brow) * K + kStart + bgl * 8;
  int bDst = brow * 128 + bgp * 16;

  f32x4 acc[4][2] = {};
  float4 rb[2];
  const int NT = kLen / 64;

#define SB() __builtin_amdgcn_sched_barrier(0)
#define ISSUE_RB(kk) { rb[0] = *(const float4*)(BpG + (kk)); \
                       rb[1] = *(const float4*)(BpG + (kk) + 4); }
#define DMA_A4(buf, kk) { _Pragma("unroll") for (int p = 0; p < 4; ++p) \
    __builtin_amdgcn_global_load_lds( \
        (const __attribute__((address_space(1))) void*)(ApG + (size_t)p * 64 * K + (kk)), \
        (__attribute__((address_space(3))) void*)((char*)&As[0][0] + (buf) * 32768 + p * 8192 + wave * 1024), \
        16, 0, 0); }
#define WRITE_RB(buf) { union { f16x2 h2[4]; uint4 q; } u; \
    u.h2[0] = pkrtz(rb[0].x, rb[0].y); u.h2[1] = pkrtz(rb[0].z, rb[0].w); \
    u.h2[2] = pkrtz(rb[1].x, rb[1].y); u.h2[3] = pkrtz(rb[1].z, rb[1].w); \
    *(uint4*)((char*)&Bs[0][0] + (buf) * 8192 + bDst) = u.q; }

  // Prologue: fully stage tile 0 into buffer 0 (one exposed drain).
  ISSUE_RB(0)
  DMA_A4(0, 0)
  WRITE_RB(0)
  __syncthreads();

  f16x8 af[4][2];
  for (int i = 0; i < NT; ++i) {
    int cur = i & 1, nxt = cur ^ 1;
    bool nx = (i + 1 < NT);
    // ================= phase 0 =================
    if (nx) { ISSUE_RB((i + 1) * 64) DMA_A4(nxt, (i + 1) * 64) }
    SB();
    if (nx) { asm volatile("s_waitcnt vmcnt(6)" ::: "memory"); }   // keep next-tile 6 in flight
    else    { asm volatile("s_waitcnt vmcnt(0)" ::: "memory"); }
    SB();
    __builtin_amdgcn_s_barrier();      // all waves: tile i fully in LDS
    SB();
    f16x8 bfp[2];
#pragma unroll
    for (int m = 0; m < 4; ++m)
#pragma unroll
      for (int kh = 0; kh < 2; ++kh) {
        int row = wr * 64 + m * 16 + frow;
        af[m][kh] = *(const f16x8*)((const char*)&As[0][0] + cur * 32768 + row * 128 +
                                    ((((kh << 2) | gq) ^ (row & 7)) << 4));
      }
    {
      int row = wc * 32 + frow;        // n = 0
#pragma unroll
      for (int kh = 0; kh < 2; ++kh)
        bfp[kh] = *(const f16x8*)((const char*)&Bs[0][0] + cur * 8192 + row * 128 +
                                  ((((kh << 2) | gq) ^ (row & 7)) << 4));
    }
    asm volatile("s_waitcnt lgkmcnt(0)" ::: "memory");
    SB();
    __builtin_amdgcn_s_setprio(1);
#pragma unroll
    for (int kh = 0; kh < 2; ++kh)
#pragma unroll
      for (int m = 0; m < 4; ++m)
        acc[m][0] = __builtin_amdgcn_mfma_f32_16x16x32_f16(af[m][kh], bfp[kh], acc[m][0], 0, 0, 0);
    __builtin_amdgcn_s_setprio(0);
    SB();
    __builtin_amdgcn_s_barrier();
    SB();
    // ================= phase 1 =================
    if (nx) WRITE_RB(nxt)              // auto-waits rb; DMAs stay in flight
    {
      int row = wc * 32 + 16 + frow;   // n = 1
#pragma unroll
      for (int kh = 0; kh < 2; ++kh)
        bfp[kh] = *(const f16x8*)((const char*)&Bs[0][0] + cur * 8192 + row * 128 +
                                  ((((kh << 2) | gq) ^ (row & 7)) << 4));
    }
    asm volatile("s_waitcnt lgkmcnt(0)" ::: "memory");
    SB();
    __builtin_amdgcn_s_setprio(1);
#pragma unroll
    for (int kh = 0; kh < 2; ++kh)
#pragma unroll
      for (int m = 0; m < 4; ++m)
        acc[m][1] = __builtin_amdgcn_mfma_f32_16x16x32_f16(af[m][kh], bfp[kh], acc[m][1], 0, 0, 0);
    __builtin_amdgcn_s_setprio(0);
    SB();
    __builtin_amdgcn_s_barrier();
    SB();
  }
#undef SB
#undef ISSUE_RB
#undef DMA_A4
#undef WRITE_RB

  // Epilogue: C/D layout col=lane&15, row=(lane>>4)*4+r
  if (z == 0) {
#pragma unroll
    for (int m = 0; m < 4; ++m) {
      int row0 = wr * 64 + m * 16 + (lane >> 4) * 4;
#pragma unroll
      for (int n = 0; n < 2; ++n) {
        int col = bcol + wc * 32 + n * 16 + frow;
#pragma unroll
        for (int r = 0; r < 4; ++r)
          C0[(size_t)(row0 + r) * ldc + col] = acc[m][n][r];
      }
    }
  } else {
    ushort* Cz = Cp + (size_t)(z - 1) * Sq * ldc;
#pragma unroll
    for (int m = 0; m < 4; ++m) {
      int row0 = wr * 64 + m * 16 + (lane >> 4) * 4;
#pragma unroll
      for (int n = 0; n < 2; ++n) {
        int col = bcol + wc * 32 + n * 16 + frow;
#pragma unroll
        for (int r = 0; r < 4; ++r)
          Cz[(size_t)(row0 + r) * ldc + col] = f2h(acc[m][n][r]);
      }
    }
  }
}

// ---------------- reg-staged MFMA GEMM (dt-fixup, compensated fp16) ----
template<int BN, bool SPLIT>
__global__ __launch_bounds__(256) void gemm_mfma(const ushort* __restrict__ A_hi,
                                                 const ushort* __restrict__ A_lo,
                                                 const float* __restrict__ B,
                                                 float* __restrict__ C,
                                                 int ldc, int K, int kLen,
                                                 int bcol0, int M) {
  constexpr int BK = 64;
  constexpr int LDA = 72;
  constexpr int N_REP = BN / 32;
  constexpr int BQN = (BN == 128) ? 8 : 4;
  __shared__ __align__(16) ushort As[64 * LDA];
  __shared__ __align__(16) ushort Bs[BN * LDA];
  __shared__ __align__(16) ushort AsL[SPLIT ? 64 * LDA : 1];
  __shared__ __align__(16) ushort BsL[SPLIT ? BN * LDA : 1];

  int t = threadIdx.x;
  int wave = t >> 6, lane = t & 63;
  int wr = wave >> 1, wc = wave & 1;
  int frow = lane & 15, fk = (lane >> 4) * 8;
  int rowBase = blockIdx.x * 64;
  int bcol = bcol0 + blockIdx.y * BN;
  int ccol = blockIdx.y * BN;
  int kStart = blockIdx.z * kLen;
  C += (size_t)blockIdx.z * M * ldc;

  int arow = t >> 2, ak = (t & 3) * 16;
  const ushort* Ap  = A_hi + (size_t)(rowBase + arow) * K + ak;
  const ushort* ApL = SPLIT ? (A_lo + (size_t)(rowBase + arow) * K + ak) : nullptr;

  int brow, bq;
  if constexpr (BN == 128) { brow = t >> 1; bq = (t & 1) * 32; }
  else                     { brow = t >> 2; bq = (t & 3) * 16; }
  const float* Bp = B + (size_t)(bcol + brow) * K + bq;

  f32x4 acc[2][N_REP] = {};
  uint4 aPre[2], aPreL[2];
  float4 bPre[BQN];

  auto loadK = [&](int kk) {
    aPre[0] = *reinterpret_cast<const uint4*>(Ap + kk);
    aPre[1] = *reinterpret_cast<const uint4*>(Ap + kk + 8);
    if constexpr (SPLIT) {
      aPreL[0] = *reinterpret_cast<const uint4*>(ApL + kk);
      aPreL[1] = *reinterpret_cast<const uint4*>(ApL + kk + 8);
    }
#pragma unroll
    for (int j = 0; j < BQN; ++j)
      bPre[j] = *reinterpret_cast<const float4*>(Bp + kk + j * 4);
  };

  loadK(kStart);
  for (int ki = 0; ki < kLen; ki += BK) {
    __syncthreads();
    *reinterpret_cast<uint4*>(&As[arow * LDA + ak])     = aPre[0];
    *reinterpret_cast<uint4*>(&As[arow * LDA + ak + 8]) = aPre[1];
    if constexpr (SPLIT) {
      *reinterpret_cast<uint4*>(&AsL[arow * LDA + ak])     = aPreL[0];
      *reinterpret_cast<uint4*>(&AsL[arow * LDA + ak + 8]) = aPreL[1];
    }
    {
      ushort hb[BQN * 4];
      ushort lb[SPLIT ? BQN * 4 : 1];
      const float* bf = reinterpret_cast<const float*>(bPre);
#pragma unroll
      for (int j = 0; j < BQN * 4; ++j) {
        hb[j] = f2h(bf[j]);
        if constexpr (SPLIT) lb[j] = f2h_lo(bf[j], hb[j]);
      }
#pragma unroll
      for (int j = 0; j < BQN / 2; ++j)
        *reinterpret_cast<uint4*>(&Bs[brow * LDA + bq + j * 8]) =
            reinterpret_cast<const uint4*>(hb)[j];
      if constexpr (SPLIT) {
#pragma unroll
        for (int j = 0; j < BQN / 2; ++j)
          *reinterpret_cast<uint4*>(&BsL[brow * LDA + bq + j * 8]) =
              reinterpret_cast<const uint4*>(lb)[j];
      }
    }
    __syncthreads();
    if (ki + BK < kLen) loadK(kStart + ki + BK);
    f16x8 af[2][2], bfv[N_REP][2];
    f16x8 afL[SPLIT ? 2 : 1][2], bfL[SPLIT ? N_REP : 1][2];
#pragma unroll
    for (int m = 0; m < 2; ++m)
#pragma unroll
      for (int kh = 0; kh < 2; ++kh) {
        af[m][kh] = *reinterpret_cast<const f16x8*>(
            &As[(wr * 32 + m * 16 + frow) * LDA + kh * 32 + fk]);
        if constexpr (SPLIT)
          afL[m][kh] = *reinterpret_cast<const f16x8*>(
              &AsL[(wr * 32 + m * 16 + frow) * LDA + kh * 32 + fk]);
      }
#pragma unroll
    for (int n = 0; n < N_REP; ++n)
#pragma unroll
      for (int kh = 0; kh < 2; ++kh) {
        bfv[n][kh] = *reinterpret_cast<const f16x8*>(
            &Bs[(wc * (BN / 2) + n * 16 + frow) * LDA + kh * 32 + fk]);
        if constexpr (SPLIT)
          bfL[n][kh] = *reinterpret_cast<const f16x8*>(
              &BsL[(wc * (BN / 2) + n * 16 + frow) * LDA + kh * 32 + fk]);
      }
#pragma unroll
    for (int kh = 0; kh < 2; ++kh)
#pragma unroll
      for (int m = 0; m < 2; ++m)
#pragma unroll
        for (int n = 0; n < N_REP; ++n) {
          acc[m][n] = __builtin_amdgcn_mfma_f32_16x16x32_f16(af[m][kh], bfv[n][kh], acc[m][n], 0, 0, 0);
          if constexpr (SPLIT) {
            acc[m][n] = __builtin_amdgcn_mfma_f32_16x16x32_f16(af[m][kh], bfL[n][kh], acc[m][n], 0, 0, 0);
            acc[m][n] = __builtin_amdgcn_mfma_f32_16x16x32_f16(afL[m][kh], bfv[n][kh], acc[m][n], 0, 0, 0);
          }
        }
  }

#pragma unroll
  for (int m = 0; m < 2; ++m) {
    int row0 = rowBase + wr * 32 + m * 16 + (lane >> 4) * 4;
#pragma unroll
    for (int n = 0; n < N_REP; ++n) {
      int col = ccol + wc * (BN / 2) + n * 16 + frow;
#pragma unroll
      for (int r = 0; r < 4; ++r)
        C[(size_t)(row0 + r) * ldc + col] = acc[m][n][r];
    }
  }
}

// ---------------- reduce in_proj: proj(f32 plane0) += 3 fp16 planes ----------
__global__ __launch_bounds__(256) void reduce_in_k(float* __restrict__ proj,
                                                   const ushort* __restrict__ pp) {
  int i = blockIdx.x * 256 + threadIdx.x;   // float4 group index
  const size_t PL = (size_t)Sq * IN_OUT;
  float4 o = reinterpret_cast<const float4*>(proj)[i];
#pragma unroll
  for (int zz = 0; zz < 3; ++zz) {
    ushort4 hv = reinterpret_cast<const ushort4*>(pp + zz * PL)[i];
    o.x += h2f(hv.x); o.y += h2f(hv.y); o.z += h2f(hv.z); o.w += h2f(hv.w);
  }
  reinterpret_cast<float4*>(proj)[i] = o;
}

// ---------------- Conv (K=4) + SiLU, with fused conv_state_out ----------------
__global__ __launch_bounds__(256) void conv_silu_k(const float* __restrict__ proj,
                                                   const float* __restrict__ cstate,
                                                   const float* __restrict__ cw,
                                                   const float* __restrict__ cb,
                                                   float* __restrict__ y,
                                                   float* __restrict__ out1) {
  int s = blockIdx.y;
  if (s == Sq) {   // fused conv_state_out
    int c = blockIdx.x * 256 + threadIdx.x;
#pragma unroll
    for (int tt = 0; tt < 3; ++tt)
      out1[c * 3 + tt] = proj[(size_t)(Sq - 3 + tt) * IN_OUT + D_INNER + c];
    return;
  }
  int c = blockIdx.x * 256 + threadIdx.x;  // 0..10239
  float acc = cb[c];
  float4 w4 = *reinterpret_cast<const float4*>(cw + c * 4);
  float wj[4] = {w4.x, w4.y, w4.z, w4.w};
#pragma unroll
  for (int j = 0; j < 4; j++) {
    int si = s + j - 3;
    float v = (si < 0) ? cstate[c * 3 + (si + 3)]
                       : proj[(size_t)si * IN_OUT + D_INNER + c];
    acc += wj[j] * v;
  }
  float sig = 1.f / (1.f + expf(-acc));
  y[(size_t)s * CONV_DIM + c] = acc * sig;
}

// ---------------- SSM scan: 4 blocks/head, float4 LDS reads, fused dt ---------
#define CS 16
__global__ __launch_bounds__(256) void ssm_scan_k(const float* __restrict__ y_conv,
                                                  const float* __restrict__ dtfix,
                                                  const float* __restrict__ dt_bias,
                                                  const float* __restrict__ sstate_in,
                                                  const float* __restrict__ A_log,
                                                  const float* __restrict__ D_param,
                                                  float* __restrict__ ys_out,
                                                  float* __restrict__ sstate_out) {
  int h = blockIdx.x >> 2;
  int pb = (blockIdx.x & 3) * 16;
  int t = threadIdx.x;
  int ng = t & 15, pl = t >> 4;
  int g = h >> 4;  // rep = NH/G = 16
  float A = -expf(A_log[h]);
  float Dp = D_param[h];
  float bias = dt_bias[h];

  float st[8];
  {
    const float* sp = sstate_in + ((size_t)h * Pd + pb + pl) * Nn + ng * 8;
    float4 v = *reinterpret_cast<const float4*>(sp);
    float4 w = *reinterpret_cast<const float4*>(sp + 4);
    st[0] = v.x; st[1] = v.y; st[2] = v.z; st[3] = v.w;
    st[4] = w.x; st[5] = w.y; st[6] = w.z; st[7] = w.w;
  }

  __shared__ __align__(16) float ybuf[CS][272];  // [0..15]=x, [16..143]=B, [144..271]=C
  __shared__ float dts[CS];
  int lr = t >> 4;
  int lc = t & 15;

  for (int ch = 0; ch < Sq / CS; ++ch) {
    int s0 = ch * CS;
    __syncthreads();
    const float* rowp = y_conv + (size_t)(s0 + lr) * CONV_DIM;
#pragma unroll
    for (int j = 0; j < 5; ++j) {
      int c = lc + 16 * j;  // f4 slot 0..79; 68 used
      if (c < 68) {
        const float* src;
        int off;
        if (c < 4)       { src = rowp + h * 64 + pb;                      off = c * 4; }
        else if (c < 36) { src = rowp + D_INNER + g * 128;                off = (c - 4) * 4; }
        else             { src = rowp + D_INNER + D_STATE + g * 128;      off = (c - 36) * 4; }
        int dst = (c < 4) ? c * 4 : (c < 36 ? 16 + (c - 4) * 4 : 144 + (c - 36) * 4);
        *reinterpret_cast<float4*>(&ybuf[lr][dst]) = *reinterpret_cast<const float4*>(src + off);
      }
    }
    if (t < CS) {   // fused dt: sum 32 split-K planes + bias -> softplus
      float v = bias;
      int idx = (s0 + t) * NH + h;
#pragma unroll
      for (int zz = 0; zz < 32; ++zz) v += dtfix[zz * (Sq * NH) + idx];
      dts[t] = (v > 20.f) ? v : log1pf(expf(v));
    }
    __syncthreads();

#pragma unroll 4
    for (int stp = 0; stp < CS; ++stp) {
      float dt = dts[stp];
      float dA = expf(dt * A);
      float x0 = ybuf[stp][pl];
      float dtx = dt * x0;
      float4 b0 = *reinterpret_cast<const float4*>(&ybuf[stp][16 + ng * 8]);
      float4 b1 = *reinterpret_cast<const float4*>(&ybuf[stp][16 + ng * 8 + 4]);
      float4 c0 = *reinterpret_cast<const float4*>(&ybuf[stp][144 + ng * 8]);
      float4 c1 = *reinterpret_cast<const float4*>(&ybuf[stp][144 + ng * 8 + 4]);
      float y0;
      st[0] = st[0] * dA + dtx * b0.x;  y0  = st[0] * c0.x;
      st[1] = st[1] * dA + dtx * b0.y;  y0 += st[1] * c0.y;
      st[2] = st[2] * dA + dtx * b0.z;  y0 += st[2] * c0.z;
      st[3] = st[3] * dA + dtx * b0.w;  y0 += st[3] * c0.w;
      st[4] = st[4] * dA + dtx * b1.x;  y0 += st[4] * c1.x;
      st[5] = st[5] * dA + dtx * b1.y;  y0 += st[5] * c1.y;
      st[6] = st[6] * dA + dtx * b1.z;  y0 += st[6] * c1.z;
      st[7] = st[7] * dA + dtx * b1.w;  y0 += st[7] * c1.w;
      y0 += __shfl_xor(y0, 1); y0 += __shfl_xor(y0, 2);
      y0 += __shfl_xor(y0, 4); y0 += __shfl_xor(y0, 8);
      if (ng == 0)
        ys_out[(size_t)(s0 + stp) * D_INNER + h * 64 + pb + pl] = y0 + Dp * x0;
    }
  }

  float* so = sstate_out + ((size_t)h * Pd + pb + pl) * Nn + ng * 8;
  *reinterpret_cast<float4*>(so)     = make_float4(st[0], st[1], st[2], st[3]);
  *reinterpret_cast<float4*>(so + 4) = make_float4(st[4], st[5], st[6], st[7]);
}

// ---------------- gate*silu + grouped RMSNorm -> fp16 ----------------
__global__ __launch_bounds__(256) void gated_norm_k(const float* __restrict__ ys,
                                                    const float* __restrict__ proj,
                                                    const float* __restrict__ w,
                                                    ushort* __restrict__ out_h) {
  int s = blockIdx.x, g = blockIdx.y, t = threadIdx.x;
  float vals[4];
  float ss = 0.f;
#pragma unroll
  for (int i = 0; i < 4; i++) {
    int d = g * 1024 + i * 256 + t;
    float gate = proj[(size_t)s * IN_OUT + d];
    float v = ys[(size_t)s * D_INNER + d] * (gate / (1.f + expf(-gate)));
    vals[i] = v;
    ss += v * v;
  }
#pragma unroll
  for (int off = 32; off > 0; off >>= 1) ss += __shfl_xor(ss, off);
  __shared__ float red[4];
  if ((t & 63) == 0) red[t >> 6] = ss;
  __syncthreads();
  ss = red[0] + red[1] + red[2] + red[3];
  float scale = rsqrtf(ss * (1.f / 1024.f) + EPSI);
#pragma unroll
  for (int i = 0; i < 4; i++) {
    int d = g * 1024 + i * 256 + t;
    out_h[(size_t)s * D_INNER + d] = f2h(vals[i] * scale * w[d]);
  }
}

// ---------------- out reduce: out0 = f32 plane0 + 7 fp16 planes + hidden ----
__global__ __launch_bounds__(256) void reduce_out_k(const float* __restrict__ p0,
                                                    const ushort* __restrict__ pph,
                                                    const float* __restrict__ hidden,
                                                    float* __restrict__ out0) {
  int i = blockIdx.x * 256 + threadIdx.x;
  const size_t PL = (size_t)Sq * Hd;
  float4 o = reinterpret_cast<const float4*>(hidden)[i];
  float4 a = reinterpret_cast<const float4*>(p0)[i];
  o.x += a.x; o.y += a.y; o.z += a.z; o.w += a.w;
#pragma unroll
  for (int zz = 0; zz < 7; ++zz) {
    ushort4 hv = reinterpret_cast<const ushort4*>(pph + zz * PL)[i];
    o.x += h2f(hv.x); o.y += h2f(hv.y); o.z += h2f(hv.z); o.w += h2f(hv.w);
  }
  reinterpret_cast<float4*>(out0)[i] = o;
}

extern "C" void kernel_launch(void* const* d_in, const int* in_sizes, int n_in,
                              void* d_out, int out_size, void* d_ws, size_t ws_size,
                              hipStream_t stream) {
  const float* hidden    = (const float*)d_in[0];
  const float* cstate_in = (const float*)d_in[1];
  const float* sstate_in = (const float*)d_in[2];
  const float* norm_w    = (const float*)d_in[3];
  const float* w_in      = (const float*)d_in[4];
  const float* conv_w    = (const float*)d_in[5];
  const float* conv_b    = (const float*)d_in[6];
  const float* A_log     = (const float*)d_in[7];
  const float* D_param   = (const float*)d_in[8];
  const float* dt_bias   = (const float*)d_in[9];
  const float* ssm_nw    = (const float*)d_in[10];
  const float* w_out     = (const float*)d_in[11];

  float* out0 = (float*)d_out;                    // [256,4096]
  float* out1 = out0 + (size_t)Sq * Hd;           // [10240,3]
  float* out2 = out1 + (size_t)CONV_DIM * 3;      // [128,64,128]

  ushort* h_hi  = (ushort*)d_ws;
  ushort* h_lo  = h_hi + (size_t)Sq * Hd;
  float*  proj  = (float*)(h_lo + (size_t)Sq * Hd);
  ushort* pp_in = (ushort*)(proj + (size_t)Sq * IN_OUT);      // 3 fp16 planes
  float*  y_conv = (float*)pp_in;                             // aliases pp_in post-reduce
  float*  dtp   = y_conv + (size_t)Sq * CONV_DIM;             // (hole)
  float*  ys    = dtp + (size_t)Sq * NH;
  ushort* ys_h  = (ushort*)(ys + (size_t)Sq * D_INNER);
  float*  dtfix = (float*)(ys_h + (size_t)Sq * D_INNER);      // 32 planes x 128KB = 4MB
  float*  op0    = (float*)d_ws;                              // out plane0 f32 (4MB)
  ushort* pp_out = (ushort*)(op0 + (size_t)Sq * Hd);          // 7 fp16 planes (14MB)

  // 1. RMSNorm -> fp16 hi/lo
  rmsnorm_k<<<Sq, 256, 0, stream>>>(hidden, norm_w, h_hi, h_lo);
  // 2. in_proj: phase-split 256x64 tiles, split-K x4. 1160 blocks x 512 thr.
  gemm_8p<<<dim3(IN_OUT / 64, 1, 4), 512, 0, stream>>>(
      h_hi, w_in, proj, pp_in, IN_OUT, Hd, Hd / 4);
  // 2r. reduce split-K planes into proj
  reduce_in_k<<<(Sq * IN_OUT / 4) / 256, 256, 0, stream>>>(proj, pp_in);
  // 2b. dt columns, compensated fp16 (~f32), split-K x32 -> 256 blocks
  gemm_mfma<64, true><<<dim3(4, 2, 32), 256, 0, stream>>>(
      h_hi, h_lo, w_in, dtfix, NH, Hd, Hd / 32, DT_COL0, Sq);
  // 3. conv + silu (+fused conv_state_out on y==Sq row)
  conv_silu_k<<<dim3(CONV_DIM / 256, Sq + 1), 256, 0, stream>>>(
      proj, cstate_in, conv_w, conv_b, y_conv, out1);
  // 4. SSM scan (4 blocks/head, fused dt softplus)
  ssm_scan_k<<<NH * 4, 256, 0, stream>>>(y_conv, dtfix, dt_bias, sstate_in,
                                         A_log, D_param, ys, out2);
  // 5. gated + grouped RMSNorm -> fp16 A for out_proj
  gated_norm_k<<<dim3(Sq, Gg), 256, 0, stream>>>(ys, proj, ssm_nw, ys_h);
  // 6. out_proj: phase-split 256x64 tiles, split-K x8. 512 blocks (1 residency round).
  gemm_8p<<<dim3(Hd / 64, 1, 8), 512, 0, stream>>>(
      ys_h, w_out, op0, pp_out, Hd, D_INNER, D_INNER / 8);
  // 7. reduce 8 partials + residual
  reduce_out_k<<<(Sq * Hd / 4) / 256, 256, 0, stream>>>(op0, pp_out, hidden, out0);
}